// Round 5
// baseline (921.013 us; speedup 1.0000x reference)
//
#include <hip/hip_runtime.h>
#include <hip/hip_bf16.h>
#include <float.h>

#define BB 8
#define DD 384
#define NQ 2048
#define NK 2048
#define NEG 0.2f

// ============================ KNN ============================
// 4 threads per query, each scans a contiguous 512-key chunk (chunk order
// preserves ascending-index tie semantics), leader merges via LDS.
#define GROUPS 4
#define CHUNK  512              // NK / GROUPS
#define QPB    64               // queries per block (256 threads / 4 groups)

// stable top-8 insert: pos = count(list <= dist) -> ties keep earlier index
// all accesses static after unroll (rule #20: no dynamic reg indexing)
#define INSERT8(BD, BI, DIST, IDX)                                    \
  {                                                                   \
    int pos = 0;                                                      \
    _Pragma("unroll")                                                 \
    for (int s = 0; s < 8; ++s) pos += (BD[s] <= (DIST)) ? 1 : 0;     \
    _Pragma("unroll")                                                 \
    for (int s = 7; s >= 1; --s) {                                    \
      bool c = BD[s - 1] > (DIST);                                    \
      BD[s] = c ? BD[s - 1] : BD[s];                                  \
      BI[s] = c ? BI[s - 1] : BI[s];                                  \
    }                                                                 \
    _Pragma("unroll")                                                 \
    for (int s = 0; s < 8; ++s) if (s == pos) { BD[s] = (DIST); BI[s] = (IDX); } \
  }

__global__ __launch_bounds__(256) void knn_kernel(
    const float* __restrict__ qc,   // (B,3,NQ)
    const float* __restrict__ kc,   // (B,3,NK)
    int* __restrict__ idx)          // (B,NQ,8)
{
  __shared__ float4 ksm[GROUPS][CHUNK + 1]; // +1 pad: chunks start on banks 0/4/8/12
  __shared__ float  md[QPB][GROUPS * 8 + 1];
  __shared__ int    mi[QPB][GROUPS * 8 + 1];

  const int b = blockIdx.y;
  const int t = threadIdx.x;

  const float* kcb = kc + (size_t)b * 3 * NK;
  for (int i = t; i < NK; i += 256) {
    float x = kcb[i], y = kcb[NK + i], z = kcb[2 * NK + i];
    ksm[i >> 9][i & (CHUNK - 1)] = make_float4(x, y, z, (x * x + y * y) + z * z);
  }
  __syncthreads();

  const int g  = t & 3;
  const int ql = t >> 2;                 // 0..63
  const int q  = blockIdx.x * QPB + ql;
  const float* qcb = qc + (size_t)b * 3 * NQ;
  const float qx = qcb[q], qy = qcb[NQ + q], qz = qcb[2 * NQ + q];
  const float q2 = (qx * qx + qy * qy) + qz * qz;

  float bd[8]; int bi[8];
  #pragma unroll
  for (int s = 0; s < 8; ++s) { bd[s] = FLT_MAX; bi[s] = 0; }

  const int jbase = g * CHUNK;
  for (int jj = 0; jj < CHUNK; ++jj) {
    float4 kv = ksm[g][jj];
    float inner = (qx * kv.x + qy * kv.y) + qz * kv.z;
    float dist  = (q2 - 2.0f * inner) + kv.w;
    if (dist < bd[7]) INSERT8(bd, bi, dist, jbase + jj);
  }

  #pragma unroll
  for (int s = 0; s < 8; ++s) { md[ql][g * 8 + s] = bd[s]; mi[ql][g * 8 + s] = bi[s]; }
  __syncthreads();

  if (g == 0) {
    for (int c = 8; c < 32; ++c) {
      float dist = md[ql][c];
      if (dist < bd[7]) { int ki = mi[ql][c]; INSERT8(bd, bi, dist, ki); }
    }
    int* op = idx + ((size_t)b * NQ + q) * 8;
    #pragma unroll
    for (int s = 0; s < 8; ++s) op[s] = bi[s];
  }
}

// ===================== Fused projection GEMMs =====================
// z = blockIdx.z in [0,16): b = z&7, mode = z>>3
//   mode 0: pk[b][n][d] = sum_f kf[b][f][n] * W[d][f]
//   mode 1: pq[b][n][d] = sum_f qf[b][f][n] * (W[d][D+f]-W[d][f]) + bias[d]
// SROA hygiene: NO address-of-private anywhere — fragments are filled
// component-wise (static indices), prefetch regs are named float4s.
// (Round-4 post-mortem: *(float4*)&a[0] punning demoted arrays to scratch:
//  VGPR=64, 948 MB spill write-back, VALUBusy 18.7%.)
__global__ __launch_bounds__(256, 4) void proj_gemm_all(
    const float* __restrict__ kf,   // (B, D, NK)
    const float* __restrict__ qf,   // (B, D, NQ)
    const float* __restrict__ W,    // (D, 2D) row-major
    const float* __restrict__ bias, // (D)
    float* __restrict__ pk,         // (B, NK, D)
    float* __restrict__ pq)         // (B, NQ, D)
{
  __shared__ float At[16][128];   // [f][n]
  __shared__ float Bt[16][132];   // [f][d], padded: 2-way max on transpose store

  const int t    = threadIdx.x;
  const int z    = blockIdx.z;
  const int b    = z & 7;
  const int mode = z >> 3;
  const int n0 = blockIdx.x * 128;
  const int d0 = blockIdx.y * 128;
  const int td = t & 15;          // d fast: coalesced epilogue
  const int tn = t >> 4;

  float acc[8][8];
  #pragma unroll
  for (int i = 0; i < 8; ++i)
    #pragma unroll
    for (int j = 0; j < 8; ++j) acc[i][j] = 0.f;

  const float* feats = mode ? qf : kf;
  float* out = mode ? pq : pk;
  const float* fb = feats + (size_t)b * DD * 2048;

  const int ar  = t >> 5;         // 0..7  (A row within half-tile)
  const int ac  = (t & 31) * 4;   // 0..124
  const int bdl = t >> 2;         // 0..63 (B d within half-tile)
  const int bf  = (t & 3) * 4;    // f offset 0/4/8/12

  float4 sa0, sa1, sw1a, sw1b, sw2a, sw2b;

#define PREFETCH(KT)                                                           \
  {                                                                            \
    sa0 = *(const float4*)&fb[(size_t)((KT) + ar) * 2048 + n0 + ac];           \
    sa1 = *(const float4*)&fb[(size_t)((KT) + ar + 8) * 2048 + n0 + ac];       \
    const float* wr0 = W + (size_t)(d0 + bdl) * (2 * DD) + (KT) + bf;          \
    const float* wr1 = W + (size_t)(d0 + bdl + 64) * (2 * DD) + (KT) + bf;     \
    sw1a = *(const float4*)wr0;                                                \
    sw1b = *(const float4*)wr1;                                                \
    if (mode) { sw2a = *(const float4*)(wr0 + DD); sw2b = *(const float4*)(wr1 + DD); } \
  }

  PREFETCH(0);

  for (int kt = 0; kt < DD; kt += 16) {
    *(float4*)&At[ar][ac]     = sa0;   // LDS stores (not private) — fine
    *(float4*)&At[ar + 8][ac] = sa1;
    {
      float4 w = sw1a;
      if (mode) { w.x = sw2a.x - w.x; w.y = sw2a.y - w.y; w.z = sw2a.z - w.z; w.w = sw2a.w - w.w; }
      Bt[bf + 0][bdl] = w.x; Bt[bf + 1][bdl] = w.y;
      Bt[bf + 2][bdl] = w.z; Bt[bf + 3][bdl] = w.w;
    }
    {
      float4 w = sw1b;
      if (mode) { w.x = sw2b.x - w.x; w.y = sw2b.y - w.y; w.z = sw2b.z - w.z; w.w = sw2b.w - w.w; }
      Bt[bf + 0][bdl + 64] = w.x; Bt[bf + 1][bdl + 64] = w.y;
      Bt[bf + 2][bdl + 64] = w.z; Bt[bf + 3][bdl + 64] = w.w;
    }
    __syncthreads();

    if (kt + 16 < DD) PREFETCH(kt + 16);   // overlap global latency w/ compute

    #pragma unroll
    for (int k = 0; k < 16; ++k) {
      float a[8], bb[8];
      {
        float4 v = *(const float4*)&At[k][tn * 4];        // LDS read, broadcast
        a[0] = v.x; a[1] = v.y; a[2] = v.z; a[3] = v.w;
        v = *(const float4*)&At[k][tn * 4 + 64];
        a[4] = v.x; a[5] = v.y; a[6] = v.z; a[7] = v.w;
        v = *(const float4*)&Bt[k][td * 4];               // LDS read, 2-way
        bb[0] = v.x; bb[1] = v.y; bb[2] = v.z; bb[3] = v.w;
        v = *(const float4*)&Bt[k][td * 4 + 64];
        bb[4] = v.x; bb[5] = v.y; bb[6] = v.z; bb[7] = v.w;
      }
      #pragma unroll
      for (int i = 0; i < 8; ++i)
        #pragma unroll
        for (int j = 0; j < 8; ++j)
          acc[i][j] = fmaf(a[i], bb[j], acc[i][j]);
    }
    __syncthreads();
  }
#undef PREFETCH

  float4 blo = make_float4(0.f, 0.f, 0.f, 0.f);
  float4 bhi = make_float4(0.f, 0.f, 0.f, 0.f);
  if (mode) {
    blo = *(const float4*)&bias[d0 + td * 4];
    bhi = *(const float4*)&bias[d0 + td * 4 + 64];
  }

  float* ob = out + (size_t)b * 2048 * DD;
  #pragma unroll
  for (int i = 0; i < 8; ++i) {
    int n = n0 + tn * 4 + (i & 3) + ((i >= 4) ? 64 : 0);
    float4 c0, c1;
    c0.x = acc[i][0] + blo.x; c0.y = acc[i][1] + blo.y;
    c0.z = acc[i][2] + blo.z; c0.w = acc[i][3] + blo.w;
    c1.x = acc[i][4] + bhi.x; c1.y = acc[i][5] + bhi.y;
    c1.z = acc[i][6] + bhi.z; c1.w = acc[i][7] + bhi.w;
    *(float4*)&ob[(size_t)n * DD + d0 + td * 4]      = c0;
    *(float4*)&ob[(size_t)n * DD + d0 + td * 4 + 64] = c1;
  }
}

// ============== Gather + max over 8 neighbors + LeakyReLU ==============
// max_k LReLU(PK_k + PQ) = LReLU(max_k PK_k + PQ)  (LReLU monotone)
__global__ __launch_bounds__(384) void gather_max_kernel(
    const float4* __restrict__ pk4,  // (B, NK, 96)
    const float4* __restrict__ pq4,  // (B, NQ, 96)
    const int* __restrict__ idx,     // (B, NQ, 8)
    float4* __restrict__ out4)       // (B, NQ, 96)
{
  const int t   = threadIdx.x;
  const int bq0 = blockIdx.x * 4;
  __shared__ int nb[4][8];
  if (t < 32) nb[t >> 3][t & 7] = idx[(size_t)(bq0 + (t >> 3)) * 8 + (t & 7)];
  __syncthreads();

  const int q_l = t / 96;            // 0..3
  const int dv  = t - q_l * 96;      // 0..95
  const int bq  = bq0 + q_l;
  const int b   = bq >> 11;          // NQ = 2048
  const float4* pkb = pk4 + (size_t)b * NK * 96;

  float4 m = make_float4(-FLT_MAX, -FLT_MAX, -FLT_MAX, -FLT_MAX);
  #pragma unroll
  for (int s = 0; s < 8; ++s) {
    float4 v = pkb[(size_t)nb[q_l][s] * 96 + dv];
    m.x = fmaxf(m.x, v.x); m.y = fmaxf(m.y, v.y);
    m.z = fmaxf(m.z, v.z); m.w = fmaxf(m.w, v.w);
  }
  float4 c = pq4[(size_t)bq * 96 + dv];
  float4 r;
  r.x = m.x + c.x; r.y = m.y + c.y; r.z = m.z + c.z; r.w = m.w + c.w;
  r.x = (r.x >= 0.f) ? r.x : NEG * r.x;
  r.y = (r.y >= 0.f) ? r.y : NEG * r.y;
  r.z = (r.z >= 0.f) ? r.z : NEG * r.z;
  r.w = (r.w >= 0.f) ? r.w : NEG * r.w;
  out4[(size_t)bq * 96 + dv] = r;
}

extern "C" void kernel_launch(void* const* d_in, const int* in_sizes, int n_in,
                              void* d_out, int out_size, void* d_ws, size_t ws_size,
                              hipStream_t stream) {
  const float* qc   = (const float*)d_in[0];
  const float* qf   = (const float*)d_in[1];
  const float* kc   = (const float*)d_in[2];
  const float* kf   = (const float*)d_in[3];
  const float* W    = (const float*)d_in[4];
  const float* bias = (const float*)d_in[5];
  float* out = (float*)d_out;

  char* ws = (char*)d_ws;
  float* pk = (float*)ws;                                   // B*NK*D f32 = 25.2 MB
  float* pq = (float*)(ws + (size_t)BB * NK * DD * 4);      // B*NQ*D f32 = 25.2 MB
  int*   ix = (int*)  (ws + (size_t)2 * BB * NK * DD * 4);  // B*NQ*8 i32 = 0.5 MB

  knn_kernel<<<dim3(NQ / QPB, BB), 256, 0, stream>>>(qc, kc, ix);
  proj_gemm_all<<<dim3(2048 / 128, DD / 128, 2 * BB), 256, 0, stream>>>(kf, qf, W, bias, pk, pq);
  gather_max_kernel<<<dim3(BB * NQ / 4), 384, 0, stream>>>(
      (const float4*)pk, (const float4*)pq, ix, (float4*)out);
}

// Round 6
// 477.709 us; speedup vs baseline: 1.9280x; 1.9280x over previous
//
#include <hip/hip_runtime.h>
#include <hip/hip_bf16.h>
#include <float.h>

#define BB 8
#define DD 384
#define NQ 2048
#define NK 2048
#define NEG 0.2f

// ============================ KNN ============================
// 4 threads per query, each scans a contiguous 512-key chunk (chunk order
// preserves ascending-index tie semantics), leader merges via LDS.
#define GROUPS 4
#define CHUNK  512              // NK / GROUPS
#define QPB    64               // queries per block (256 threads / 4 groups)

// stable top-8 insert: pos = count(list <= dist) -> ties keep earlier index
// all accesses static after unroll (rule #20: no dynamic reg indexing)
#define INSERT8(BD, BI, DIST, IDX)                                    \
  {                                                                   \
    int pos = 0;                                                      \
    _Pragma("unroll")                                                 \
    for (int s = 0; s < 8; ++s) pos += (BD[s] <= (DIST)) ? 1 : 0;     \
    _Pragma("unroll")                                                 \
    for (int s = 7; s >= 1; --s) {                                    \
      bool c = BD[s - 1] > (DIST);                                    \
      BD[s] = c ? BD[s - 1] : BD[s];                                  \
      BI[s] = c ? BI[s - 1] : BI[s];                                  \
    }                                                                 \
    _Pragma("unroll")                                                 \
    for (int s = 0; s < 8; ++s) if (s == pos) { BD[s] = (DIST); BI[s] = (IDX); } \
  }

__global__ __launch_bounds__(256) void knn_kernel(
    const float* __restrict__ qc,   // (B,3,NQ)
    const float* __restrict__ kc,   // (B,3,NK)
    int* __restrict__ idx)          // (B,NQ,8)
{
  __shared__ float4 ksm[GROUPS][CHUNK + 1]; // +1 pad: chunks start on banks 0/4/8/12
  __shared__ float  md[QPB][GROUPS * 8 + 1];
  __shared__ int    mi[QPB][GROUPS * 8 + 1];

  const int b = blockIdx.y;
  const int t = threadIdx.x;

  const float* kcb = kc + (size_t)b * 3 * NK;
  for (int i = t; i < NK; i += 256) {
    float x = kcb[i], y = kcb[NK + i], z = kcb[2 * NK + i];
    ksm[i >> 9][i & (CHUNK - 1)] = make_float4(x, y, z, (x * x + y * y) + z * z);
  }
  __syncthreads();

  const int g  = t & 3;
  const int ql = t >> 2;                 // 0..63
  const int q  = blockIdx.x * QPB + ql;
  const float* qcb = qc + (size_t)b * 3 * NQ;
  const float qx = qcb[q], qy = qcb[NQ + q], qz = qcb[2 * NQ + q];
  const float q2 = (qx * qx + qy * qy) + qz * qz;

  float bd[8]; int bi[8];
  #pragma unroll
  for (int s = 0; s < 8; ++s) { bd[s] = FLT_MAX; bi[s] = 0; }

  const int jbase = g * CHUNK;
  for (int jj = 0; jj < CHUNK; ++jj) {
    float4 kv = ksm[g][jj];
    float inner = (qx * kv.x + qy * kv.y) + qz * kv.z;
    float dist  = (q2 - 2.0f * inner) + kv.w;
    if (dist < bd[7]) INSERT8(bd, bi, dist, jbase + jj);
  }

  #pragma unroll
  for (int s = 0; s < 8; ++s) { md[ql][g * 8 + s] = bd[s]; mi[ql][g * 8 + s] = bi[s]; }
  __syncthreads();

  if (g == 0) {
    for (int c = 8; c < 32; ++c) {
      float dist = md[ql][c];
      if (dist < bd[7]) { int ki = mi[ql][c]; INSERT8(bd, bi, dist, ki); }
    }
    int* op = idx + ((size_t)b * NQ + q) * 8;
    #pragma unroll
    for (int s = 0; s < 8; ++s) op[s] = bi[s];
  }
}

// ===================== Fused projection GEMMs =====================
// z = blockIdx.z in [0,16): b = z&7, mode = z>>3
//   mode 0: pk[b][n][d] = sum_f kf[b][f][n] * W[d][f]
//   mode 1: pq[b][n][d] = sum_f qf[b][f][n] * (W[d][D+f]-W[d][f]) + bias[d]
// NOTE: NO second __launch_bounds__ arg. Rounds 4/5 post-mortem: (256,4)
// made the allocator cap at exactly 64 VGPRs (the 8-waves/SIMD breakpoint)
// and spill the 64-reg accumulator -> 1.5 GB scratch write-back, 12% VALU.
// Grid is 3 blocks/CU (grid-limited) so the occupancy hint bought nothing.
__global__ __launch_bounds__(256) void proj_gemm_all(
    const float* __restrict__ kf,   // (B, D, NK)
    const float* __restrict__ qf,   // (B, D, NQ)
    const float* __restrict__ W,    // (D, 2D) row-major
    const float* __restrict__ bias, // (D)
    float* __restrict__ pk,         // (B, NK, D)
    float* __restrict__ pq)         // (B, NQ, D)
{
  __shared__ float At[16][128];   // [f][n]
  __shared__ float Bt[16][132];   // [f][d], padded: 2-way max on transpose store

  const int t    = threadIdx.x;
  const int z    = blockIdx.z;
  const int b    = z & 7;
  const int mode = z >> 3;
  const int n0 = blockIdx.x * 128;
  const int d0 = blockIdx.y * 128;
  const int td = t & 15;          // d fast: coalesced epilogue
  const int tn = t >> 4;

  float acc[8][8];
  #pragma unroll
  for (int i = 0; i < 8; ++i)
    #pragma unroll
    for (int j = 0; j < 8; ++j) acc[i][j] = 0.f;

  const float* feats = mode ? qf : kf;
  float* out = mode ? pq : pk;
  const float* fb = feats + (size_t)b * DD * 2048;

  const int ar  = t >> 5;         // 0..7  (A row within half-tile)
  const int ac  = (t & 31) * 4;   // 0..124
  const int bdl = t >> 2;         // 0..63 (B d within half-tile)
  const int bf  = (t & 3) * 4;    // f offset 0/4/8/12

  float4 sa0, sa1, sw1a, sw1b, sw2a, sw2b;

#define PREFETCH(KT)                                                           \
  {                                                                            \
    sa0 = *(const float4*)&fb[(size_t)((KT) + ar) * 2048 + n0 + ac];           \
    sa1 = *(const float4*)&fb[(size_t)((KT) + ar + 8) * 2048 + n0 + ac];       \
    const float* wr0 = W + (size_t)(d0 + bdl) * (2 * DD) + (KT) + bf;          \
    const float* wr1 = W + (size_t)(d0 + bdl + 64) * (2 * DD) + (KT) + bf;     \
    sw1a = *(const float4*)wr0;                                                \
    sw1b = *(const float4*)wr1;                                                \
    if (mode) { sw2a = *(const float4*)(wr0 + DD); sw2b = *(const float4*)(wr1 + DD); } \
  }

  PREFETCH(0);

  for (int kt = 0; kt < DD; kt += 16) {
    *(float4*)&At[ar][ac]     = sa0;   // LDS stores (not private) — fine
    *(float4*)&At[ar + 8][ac] = sa1;
    {
      float4 w = sw1a;
      if (mode) { w.x = sw2a.x - w.x; w.y = sw2a.y - w.y; w.z = sw2a.z - w.z; w.w = sw2a.w - w.w; }
      Bt[bf + 0][bdl] = w.x; Bt[bf + 1][bdl] = w.y;
      Bt[bf + 2][bdl] = w.z; Bt[bf + 3][bdl] = w.w;
    }
    {
      float4 w = sw1b;
      if (mode) { w.x = sw2b.x - w.x; w.y = sw2b.y - w.y; w.z = sw2b.z - w.z; w.w = sw2b.w - w.w; }
      Bt[bf + 0][bdl + 64] = w.x; Bt[bf + 1][bdl + 64] = w.y;
      Bt[bf + 2][bdl + 64] = w.z; Bt[bf + 3][bdl + 64] = w.w;
    }
    __syncthreads();

    if (kt + 16 < DD) PREFETCH(kt + 16);   // overlap global latency w/ compute

    #pragma unroll
    for (int k = 0; k < 16; ++k) {
      float a[8], bb[8];
      {
        float4 v = *(const float4*)&At[k][tn * 4];        // LDS read, broadcast
        a[0] = v.x; a[1] = v.y; a[2] = v.z; a[3] = v.w;
        v = *(const float4*)&At[k][tn * 4 + 64];
        a[4] = v.x; a[5] = v.y; a[6] = v.z; a[7] = v.w;
        v = *(const float4*)&Bt[k][td * 4];               // LDS read, 2-way
        bb[0] = v.x; bb[1] = v.y; bb[2] = v.z; bb[3] = v.w;
        v = *(const float4*)&Bt[k][td * 4 + 64];
        bb[4] = v.x; bb[5] = v.y; bb[6] = v.z; bb[7] = v.w;
      }
      #pragma unroll
      for (int i = 0; i < 8; ++i)
        #pragma unroll
        for (int j = 0; j < 8; ++j)
          acc[i][j] = fmaf(a[i], bb[j], acc[i][j]);
    }
    __syncthreads();
  }
#undef PREFETCH

  float4 blo = make_float4(0.f, 0.f, 0.f, 0.f);
  float4 bhi = make_float4(0.f, 0.f, 0.f, 0.f);
  if (mode) {
    blo = *(const float4*)&bias[d0 + td * 4];
    bhi = *(const float4*)&bias[d0 + td * 4 + 64];
  }

  float* ob = out + (size_t)b * 2048 * DD;
  #pragma unroll
  for (int i = 0; i < 8; ++i) {
    int n = n0 + tn * 4 + (i & 3) + ((i >= 4) ? 64 : 0);
    float4 c0, c1;
    c0.x = acc[i][0] + blo.x; c0.y = acc[i][1] + blo.y;
    c0.z = acc[i][2] + blo.z; c0.w = acc[i][3] + blo.w;
    c1.x = acc[i][4] + bhi.x; c1.y = acc[i][5] + bhi.y;
    c1.z = acc[i][6] + bhi.z; c1.w = acc[i][7] + bhi.w;
    *(float4*)&ob[(size_t)n * DD + d0 + td * 4]      = c0;
    *(float4*)&ob[(size_t)n * DD + d0 + td * 4 + 64] = c1;
  }
}

// ============== Gather + max over 8 neighbors + LeakyReLU ==============
// max_k LReLU(PK_k + PQ) = LReLU(max_k PK_k + PQ)  (LReLU monotone)
__global__ __launch_bounds__(384) void gather_max_kernel(
    const float4* __restrict__ pk4,  // (B, NK, 96)
    const float4* __restrict__ pq4,  // (B, NQ, 96)
    const int* __restrict__ idx,     // (B, NQ, 8)
    float4* __restrict__ out4)       // (B, NQ, 96)
{
  const int t   = threadIdx.x;
  const int bq0 = blockIdx.x * 4;
  __shared__ int nb[4][8];
  if (t < 32) nb[t >> 3][t & 7] = idx[(size_t)(bq0 + (t >> 3)) * 8 + (t & 7)];
  __syncthreads();

  const int q_l = t / 96;            // 0..3
  const int dv  = t - q_l * 96;      // 0..95
  const int bq  = bq0 + q_l;
  const int b   = bq >> 11;          // NQ = 2048
  const float4* pkb = pk4 + (size_t)b * NK * 96;

  float4 m = make_float4(-FLT_MAX, -FLT_MAX, -FLT_MAX, -FLT_MAX);
  #pragma unroll
  for (int s = 0; s < 8; ++s) {
    float4 v = pkb[(size_t)nb[q_l][s] * 96 + dv];
    m.x = fmaxf(m.x, v.x); m.y = fmaxf(m.y, v.y);
    m.z = fmaxf(m.z, v.z); m.w = fmaxf(m.w, v.w);
  }
  float4 c = pq4[(size_t)bq * 96 + dv];
  float4 r;
  r.x = m.x + c.x; r.y = m.y + c.y; r.z = m.z + c.z; r.w = m.w + c.w;
  r.x = (r.x >= 0.f) ? r.x : NEG * r.x;
  r.y = (r.y >= 0.f) ? r.y : NEG * r.y;
  r.z = (r.z >= 0.f) ? r.z : NEG * r.z;
  r.w = (r.w >= 0.f) ? r.w : NEG * r.w;
  out4[(size_t)bq * 96 + dv] = r;
}

extern "C" void kernel_launch(void* const* d_in, const int* in_sizes, int n_in,
                              void* d_out, int out_size, void* d_ws, size_t ws_size,
                              hipStream_t stream) {
  const float* qc   = (const float*)d_in[0];
  const float* qf   = (const float*)d_in[1];
  const float* kc   = (const float*)d_in[2];
  const float* kf   = (const float*)d_in[3];
  const float* W    = (const float*)d_in[4];
  const float* bias = (const float*)d_in[5];
  float* out = (float*)d_out;

  char* ws = (char*)d_ws;
  float* pk = (float*)ws;                                   // B*NK*D f32 = 25.2 MB
  float* pq = (float*)(ws + (size_t)BB * NK * DD * 4);      // B*NQ*D f32 = 25.2 MB
  int*   ix = (int*)  (ws + (size_t)2 * BB * NK * DD * 4);  // B*NQ*8 i32 = 0.5 MB

  knn_kernel<<<dim3(NQ / QPB, BB), 256, 0, stream>>>(qc, kc, ix);
  proj_gemm_all<<<dim3(2048 / 128, DD / 128, 2 * BB), 256, 0, stream>>>(kf, qf, W, bias, pk, pq);
  gather_max_kernel<<<dim3(BB * NQ / 4), 384, 0, stream>>>(
      (const float4*)pk, (const float4*)pq, ix, (float4*)out);
}

// Round 7
// 304.162 us; speedup vs baseline: 3.0280x; 1.5706x over previous
//
#include <hip/hip_runtime.h>
#include <hip/hip_bf16.h>
#include <float.h>

#define BB 8
#define DD 384
#define NQ 2048
#define NK 2048
#define NEG 0.2f

// ============================ KNN (wave-cooperative) ============================
// One wave per query. Lane l computes dists for keys {j*64+l, j=0..31} into 32
// statically-indexed regs (no insert sort). Then 8 extraction rounds:
//   per-lane argmin (static unroll) -> 6-step shfl_xor lexicographic (dist,key)
//   min-reduce -> winner slot masked to +INF (predicated static loop).
// Tie semantics == jax top_k: output ascending (dist, key index).
// (Round-6 post-mortem: old 4-lane-group insert-sort version ran at 263 us:
//  1 wave/SIMD (11% occ) exposed all LDS latency, and the any-lane-divergent
//  INSERT8 (~70 VALU) executed nearly every one of 512 iterations.)
#define QPW 4                    // queries per wave; block = 4 waves = 16 queries

__global__ __launch_bounds__(256) void knn_kernel(
    const float* __restrict__ qc,   // (B,3,NQ)
    const float* __restrict__ kc,   // (B,3,NK)
    int* __restrict__ idx)          // (B,NQ,8)
{
  __shared__ float4 ksm[NK];        // 32 KB: (x,y,z,|k|^2)

  const int b = blockIdx.y;
  const int t = threadIdx.x;

  const float* kcb = kc + (size_t)b * 3 * NK;
  for (int i = t; i < NK; i += 256) {
    float x = kcb[i], y = kcb[NK + i], z = kcb[2 * NK + i];
    ksm[i] = make_float4(x, y, z, (x * x + y * y) + z * z);
  }
  __syncthreads();

  const int w = t >> 6;             // wave 0..3
  const int l = t & 63;             // lane
  const float* qcb = qc + (size_t)b * 3 * NQ;

  for (int qi = 0; qi < QPW; ++qi) {
    const int q = blockIdx.x * (4 * QPW) + w * QPW + qi;
    const float qx = qcb[q], qy = qcb[NQ + q], qz = qcb[2 * NQ + q];
    const float q2 = (qx * qx + qy * qy) + qz * qz;

    // 32 distances per lane, statically indexed (same fp order as verified rounds)
    float d[32];
    #pragma unroll
    for (int j = 0; j < 32; ++j) {
      float4 kv = ksm[j * 64 + l];
      float inner = (qx * kv.x + qy * kv.y) + qz * kv.z;
      d[j] = (q2 - 2.0f * inner) + kv.w;
    }

    int outk[8];
    #pragma unroll
    for (int r = 0; r < 8; ++r) {
      // per-lane argmin; ascending scan + strict '<' => smaller j (= smaller key) wins ties
      float m = d[0]; int mj = 0;
      #pragma unroll
      for (int j = 1; j < 32; ++j) {
        bool c = d[j] < m;
        m  = c ? d[j] : m;
        mj = c ? j : mj;
      }
      int mkey = mj * 64 + l;
      // wave-wide lexicographic (dist, key) min
      #pragma unroll
      for (int off = 32; off >= 1; off >>= 1) {
        float om = __shfl_xor(m, off);
        int   ok = __shfl_xor(mkey, off);
        bool take = (om < m) || (om == m && ok < mkey);
        m    = take ? om : m;
        mkey = take ? ok : mkey;
      }
      outk[r] = mkey;                       // uniform across wave
      // mask out winner's slot (only owning lane matches l == mkey&63)
      const bool mine = (l == (mkey & 63));
      const int  slot = mkey >> 6;
      #pragma unroll
      for (int j = 0; j < 32; ++j) {
        bool kill = mine && (j == slot);
        d[j] = kill ? FLT_MAX : d[j];
      }
    }

    // lane r stores outk[r], selected via static cndmask chain
    int myv = outk[0];
    #pragma unroll
    for (int r = 1; r < 8; ++r) myv = (l == r) ? outk[r] : myv;
    if (l < 8) idx[((size_t)b * NQ + q) * 8 + l] = myv;
  }
}

// ===================== Fused projection GEMMs =====================
// z = blockIdx.z in [0,16): b = z&7, mode = z>>3
//   mode 0: pk[b][n][d] = sum_f kf[b][f][n] * W[d][f]
//   mode 1: pq[b][n][d] = sum_f qf[b][f][n] * (W[d][D+f]-W[d][f]) + bias[d]
// NOTE: NO second __launch_bounds__ arg. Rounds 4/5 post-mortem: (256,4)
// made the allocator cap at exactly 64 VGPRs (the 8-waves/SIMD breakpoint)
// and spill the 64-reg accumulator -> 1.5 GB scratch write-back, 12% VALU.
__global__ __launch_bounds__(256) void proj_gemm_all(
    const float* __restrict__ kf,   // (B, D, NK)
    const float* __restrict__ qf,   // (B, D, NQ)
    const float* __restrict__ W,    // (D, 2D) row-major
    const float* __restrict__ bias, // (D)
    float* __restrict__ pk,         // (B, NK, D)
    float* __restrict__ pq)         // (B, NQ, D)
{
  __shared__ float At[16][128];   // [f][n]
  __shared__ float Bt[16][132];   // [f][d], padded: 2-way max on transpose store

  const int t    = threadIdx.x;
  const int z    = blockIdx.z;
  const int b    = z & 7;
  const int mode = z >> 3;
  const int n0 = blockIdx.x * 128;
  const int d0 = blockIdx.y * 128;
  const int td = t & 15;          // d fast: coalesced epilogue
  const int tn = t >> 4;

  float acc[8][8];
  #pragma unroll
  for (int i = 0; i < 8; ++i)
    #pragma unroll
    for (int j = 0; j < 8; ++j) acc[i][j] = 0.f;

  const float* feats = mode ? qf : kf;
  float* out = mode ? pq : pk;
  const float* fb = feats + (size_t)b * DD * 2048;

  const int ar  = t >> 5;         // 0..7  (A row within half-tile)
  const int ac  = (t & 31) * 4;   // 0..124
  const int bdl = t >> 2;         // 0..63 (B d within half-tile)
  const int bf  = (t & 3) * 4;    // f offset 0/4/8/12

  float4 sa0, sa1, sw1a, sw1b, sw2a, sw2b;

#define PREFETCH(KT)                                                           \
  {                                                                            \
    sa0 = *(const float4*)&fb[(size_t)((KT) + ar) * 2048 + n0 + ac];           \
    sa1 = *(const float4*)&fb[(size_t)((KT) + ar + 8) * 2048 + n0 + ac];       \
    const float* wr0 = W + (size_t)(d0 + bdl) * (2 * DD) + (KT) + bf;          \
    const float* wr1 = W + (size_t)(d0 + bdl + 64) * (2 * DD) + (KT) + bf;     \
    sw1a = *(const float4*)wr0;                                                \
    sw1b = *(const float4*)wr1;                                                \
    if (mode) { sw2a = *(const float4*)(wr0 + DD); sw2b = *(const float4*)(wr1 + DD); } \
  }

  PREFETCH(0);

  for (int kt = 0; kt < DD; kt += 16) {
    *(float4*)&At[ar][ac]     = sa0;   // LDS stores (not private) — fine
    *(float4*)&At[ar + 8][ac] = sa1;
    {
      float4 w = sw1a;
      if (mode) { w.x = sw2a.x - w.x; w.y = sw2a.y - w.y; w.z = sw2a.z - w.z; w.w = sw2a.w - w.w; }
      Bt[bf + 0][bdl] = w.x; Bt[bf + 1][bdl] = w.y;
      Bt[bf + 2][bdl] = w.z; Bt[bf + 3][bdl] = w.w;
    }
    {
      float4 w = sw1b;
      if (mode) { w.x = sw2b.x - w.x; w.y = sw2b.y - w.y; w.z = sw2b.z - w.z; w.w = sw2b.w - w.w; }
      Bt[bf + 0][bdl + 64] = w.x; Bt[bf + 1][bdl + 64] = w.y;
      Bt[bf + 2][bdl + 64] = w.z; Bt[bf + 3][bdl + 64] = w.w;
    }
    __syncthreads();

    if (kt + 16 < DD) PREFETCH(kt + 16);   // overlap global latency w/ compute

    #pragma unroll
    for (int k = 0; k < 16; ++k) {
      float a[8], bb[8];
      {
        float4 v = *(const float4*)&At[k][tn * 4];        // LDS read, broadcast
        a[0] = v.x; a[1] = v.y; a[2] = v.z; a[3] = v.w;
        v = *(const float4*)&At[k][tn * 4 + 64];
        a[4] = v.x; a[5] = v.y; a[6] = v.z; a[7] = v.w;
        v = *(const float4*)&Bt[k][td * 4];               // LDS read, 2-way
        bb[0] = v.x; bb[1] = v.y; bb[2] = v.z; bb[3] = v.w;
        v = *(const float4*)&Bt[k][td * 4 + 64];
        bb[4] = v.x; bb[5] = v.y; bb[6] = v.z; bb[7] = v.w;
      }
      #pragma unroll
      for (int i = 0; i < 8; ++i)
        #pragma unroll
        for (int j = 0; j < 8; ++j)
          acc[i][j] = fmaf(a[i], bb[j], acc[i][j]);
    }
    __syncthreads();
  }
#undef PREFETCH

  float4 blo = make_float4(0.f, 0.f, 0.f, 0.f);
  float4 bhi = make_float4(0.f, 0.f, 0.f, 0.f);
  if (mode) {
    blo = *(const float4*)&bias[d0 + td * 4];
    bhi = *(const float4*)&bias[d0 + td * 4 + 64];
  }

  float* ob = out + (size_t)b * 2048 * DD;
  #pragma unroll
  for (int i = 0; i < 8; ++i) {
    int n = n0 + tn * 4 + (i & 3) + ((i >= 4) ? 64 : 0);
    float4 c0, c1;
    c0.x = acc[i][0] + blo.x; c0.y = acc[i][1] + blo.y;
    c0.z = acc[i][2] + blo.z; c0.w = acc[i][3] + blo.w;
    c1.x = acc[i][4] + bhi.x; c1.y = acc[i][5] + bhi.y;
    c1.z = acc[i][6] + bhi.z; c1.w = acc[i][7] + bhi.w;
    *(float4*)&ob[(size_t)n * DD + d0 + td * 4]      = c0;
    *(float4*)&ob[(size_t)n * DD + d0 + td * 4 + 64] = c1;
  }
}

// ============== Gather + max over 8 neighbors + LeakyReLU ==============
// max_k LReLU(PK_k + PQ) = LReLU(max_k PK_k + PQ)  (LReLU monotone)
__global__ __launch_bounds__(384) void gather_max_kernel(
    const float4* __restrict__ pk4,  // (B, NK, 96)
    const float4* __restrict__ pq4,  // (B, NQ, 96)
    const int* __restrict__ idx,     // (B, NQ, 8)
    float4* __restrict__ out4)       // (B, NQ, 96)
{
  const int t   = threadIdx.x;
  const int bq0 = blockIdx.x * 4;
  __shared__ int nb[4][8];
  if (t < 32) nb[t >> 3][t & 7] = idx[(size_t)(bq0 + (t >> 3)) * 8 + (t & 7)];
  __syncthreads();

  const int q_l = t / 96;            // 0..3
  const int dv  = t - q_l * 96;      // 0..95
  const int bq  = bq0 + q_l;
  const int b   = bq >> 11;          // NQ = 2048
  const float4* pkb = pk4 + (size_t)b * NK * 96;

  float4 m = make_float4(-FLT_MAX, -FLT_MAX, -FLT_MAX, -FLT_MAX);
  #pragma unroll
  for (int s = 0; s < 8; ++s) {
    float4 v = pkb[(size_t)nb[q_l][s] * 96 + dv];
    m.x = fmaxf(m.x, v.x); m.y = fmaxf(m.y, v.y);
    m.z = fmaxf(m.z, v.z); m.w = fmaxf(m.w, v.w);
  }
  float4 c = pq4[(size_t)bq * 96 + dv];
  float4 r;
  r.x = m.x + c.x; r.y = m.y + c.y; r.z = m.z + c.z; r.w = m.w + c.w;
  r.x = (r.x >= 0.f) ? r.x : NEG * r.x;
  r.y = (r.y >= 0.f) ? r.y : NEG * r.y;
  r.z = (r.z >= 0.f) ? r.z : NEG * r.z;
  r.w = (r.w >= 0.f) ? r.w : NEG * r.w;
  out4[(size_t)bq * 96 + dv] = r;
}

extern "C" void kernel_launch(void* const* d_in, const int* in_sizes, int n_in,
                              void* d_out, int out_size, void* d_ws, size_t ws_size,
                              hipStream_t stream) {
  const float* qc   = (const float*)d_in[0];
  const float* qf   = (const float*)d_in[1];
  const float* kc   = (const float*)d_in[2];
  const float* kf   = (const float*)d_in[3];
  const float* W    = (const float*)d_in[4];
  const float* bias = (const float*)d_in[5];
  float* out = (float*)d_out;

  char* ws = (char*)d_ws;
  float* pk = (float*)ws;                                   // B*NK*D f32 = 25.2 MB
  float* pq = (float*)(ws + (size_t)BB * NK * DD * 4);      // B*NQ*D f32 = 25.2 MB
  int*   ix = (int*)  (ws + (size_t)2 * BB * NK * DD * 4);  // B*NQ*8 i32 = 0.5 MB

  knn_kernel<<<dim3(NQ / (4 * QPW), BB), 256, 0, stream>>>(qc, kc, ix);
  proj_gemm_all<<<dim3(2048 / 128, DD / 128, 2 * BB), 256, 0, stream>>>(kf, qf, W, bias, pk, pq);
  gather_max_kernel<<<dim3(BB * NQ / 4), 384, 0, stream>>>(
      (const float4*)pk, (const float4*)pq, ix, (float4*)out);
}

// Round 8
// 264.370 us; speedup vs baseline: 3.4838x; 1.1505x over previous
//
#include <hip/hip_runtime.h>
#include <hip/hip_bf16.h>
#include <float.h>

#define BB 8
#define DD 384
#define NQ 2048
#define NK 2048
#define NEG 0.2f

typedef __attribute__((ext_vector_type(8))) __bf16 bf16x8v;
typedef __attribute__((ext_vector_type(4))) float  float4v;

__device__ __forceinline__ unsigned short bf16_rne(float x) {
  unsigned int u = __float_as_uint(x);
  return (unsigned short)((u + 0x7FFFu + ((u >> 16) & 1u)) >> 16);
}
__device__ __forceinline__ float bf16_to_f32(unsigned short h) {
  return __uint_as_float(((unsigned int)h) << 16);
}

// ============================ KNN (wave-cooperative) ============================
// One wave per query; verified at round 7 (dropped 263 -> out of top-5).
#define QPW 4

__global__ __launch_bounds__(256) void knn_kernel(
    const float* __restrict__ qc, const float* __restrict__ kc,
    int* __restrict__ idx)
{
  __shared__ float4 ksm[NK];
  const int b = blockIdx.y;
  const int t = threadIdx.x;
  const float* kcb = kc + (size_t)b * 3 * NK;
  for (int i = t; i < NK; i += 256) {
    float x = kcb[i], y = kcb[NK + i], z = kcb[2 * NK + i];
    ksm[i] = make_float4(x, y, z, (x * x + y * y) + z * z);
  }
  __syncthreads();

  const int w = t >> 6, l = t & 63;
  const float* qcb = qc + (size_t)b * 3 * NQ;

  for (int qi = 0; qi < QPW; ++qi) {
    const int q = blockIdx.x * (4 * QPW) + w * QPW + qi;
    const float qx = qcb[q], qy = qcb[NQ + q], qz = qcb[2 * NQ + q];
    const float q2 = (qx * qx + qy * qy) + qz * qz;

    float d[32];
    #pragma unroll
    for (int j = 0; j < 32; ++j) {
      float4 kv = ksm[j * 64 + l];
      float inner = (qx * kv.x + qy * kv.y) + qz * kv.z;
      d[j] = (q2 - 2.0f * inner) + kv.w;
    }

    int outk[8];
    #pragma unroll
    for (int r = 0; r < 8; ++r) {
      float m = d[0]; int mj = 0;
      #pragma unroll
      for (int j = 1; j < 32; ++j) {
        bool c = d[j] < m;
        m  = c ? d[j] : m;
        mj = c ? j : mj;
      }
      int mkey = mj * 64 + l;
      #pragma unroll
      for (int off = 32; off >= 1; off >>= 1) {
        float om = __shfl_xor(m, off);
        int   ok = __shfl_xor(mkey, off);
        bool take = (om < m) || (om == m && ok < mkey);
        m    = take ? om : m;
        mkey = take ? ok : mkey;
      }
      outk[r] = mkey;
      const bool mine = (l == (mkey & 63));
      const int  slot = mkey >> 6;
      #pragma unroll
      for (int j = 0; j < 32; ++j) {
        bool kill = mine && (j == slot);
        d[j] = kill ? FLT_MAX : d[j];
      }
    }
    int myv = outk[0];
    #pragma unroll
    for (int r = 1; r < 8; ++r) myv = (l == r) ? outk[r] : myv;
    if (l < 8) idx[((size_t)b * NQ + q) * 8 + l] = myv;
  }
}

// ================= Pre-pass 1: feats transpose + bf16 hi/lo split =================
// in:  kf/qf (B, D, 2048) f32;  out: Apk[z = src*8+b][n][hi DD | lo DD] bf16
__global__ __launch_bounds__(256) void transpose_pack_kernel(
    const float* __restrict__ kf, const float* __restrict__ qf,
    unsigned short* __restrict__ Apk)
{
  __shared__ float tile[64][68];   // 272B row stride: 16B aligned, 2-way max
  const int t = threadIdx.x;
  const int z = blockIdx.z;
  const int b = z & 7;
  const float* src = ((z >> 3) ? qf : kf) + (size_t)b * DD * 2048;
  const int f0 = blockIdx.y * 64;
  const int n0 = blockIdx.x * 64;

  {
    const int fr = t >> 2, nc = (t & 3) * 16;
    const float* p = src + (size_t)(f0 + fr) * 2048 + n0 + nc;
    float4 v0 = *(const float4*)(p);
    float4 v1 = *(const float4*)(p + 4);
    float4 v2 = *(const float4*)(p + 8);
    float4 v3 = *(const float4*)(p + 12);
    *(float4*)&tile[fr][nc]      = v0;
    *(float4*)&tile[fr][nc + 4]  = v1;
    *(float4*)&tile[fr][nc + 8]  = v2;
    *(float4*)&tile[fr][nc + 12] = v3;
  }
  __syncthreads();
  {
    const int nr = t >> 2, fc = (t & 3) * 16;
    unsigned int hp[8], lp[8];
    #pragma unroll
    for (int i = 0; i < 8; ++i) {
      float va = tile[fc + 2 * i][nr];
      float vb = tile[fc + 2 * i + 1][nr];
      unsigned short ha = bf16_rne(va), hb = bf16_rne(vb);
      unsigned short la = bf16_rne(va - bf16_to_f32(ha));
      unsigned short lb = bf16_rne(vb - bf16_to_f32(hb));
      hp[i] = (unsigned int)ha | ((unsigned int)hb << 16);
      lp[i] = (unsigned int)la | ((unsigned int)lb << 16);
    }
    unsigned short* row = Apk + ((size_t)z * 2048 + n0 + nr) * (2 * DD);
    *(uint4*)(row + f0 + fc)          = make_uint4(hp[0], hp[1], hp[2], hp[3]);
    *(uint4*)(row + f0 + fc + 8)      = make_uint4(hp[4], hp[5], hp[6], hp[7]);
    *(uint4*)(row + DD + f0 + fc)     = make_uint4(lp[0], lp[1], lp[2], lp[3]);
    *(uint4*)(row + DD + f0 + fc + 8) = make_uint4(lp[4], lp[5], lp[6], lp[7]);
  }
}

// ================= Pre-pass 2: W pack =================
// out: Wpk[mode][d][hi DD | lo DD] bf16; mode0 = W1, mode1 = W2 - W1
__global__ __launch_bounds__(192) void wpack_kernel(
    const float* __restrict__ W, unsigned short* __restrict__ Wpk)
{
  const int d = blockIdx.x;
  const int mode = blockIdx.y;
  const int t = threadIdx.x;            // 2 f each
  const float* wrow = W + (size_t)d * (2 * DD) + t * 2;
  float2 w1 = *(const float2*)(wrow);
  float a = w1.x, c = w1.y;
  if (mode) {
    float2 w2 = *(const float2*)(wrow + DD);
    a = w2.x - a; c = w2.y - c;
  }
  unsigned short ha = bf16_rne(a), hc = bf16_rne(c);
  unsigned short la = bf16_rne(a - bf16_to_f32(ha));
  unsigned short lc = bf16_rne(c - bf16_to_f32(hc));
  unsigned short* orow = Wpk + ((size_t)mode * DD + d) * (2 * DD);
  *(unsigned int*)(orow + t * 2)      = (unsigned int)ha | ((unsigned int)hc << 16);
  *(unsigned int*)(orow + DD + t * 2) = (unsigned int)la | ((unsigned int)lc << 16);
}

// ================= MFMA GEMM (bf16x3 split: hi*hi + hi*lo + lo*hi) =================
// C[n][d] = sum_f A[n][f] * Wsel[d][f]; M=n, N=d, K=f, 16x16x32 frags.
// A-frag: row=lane&15, k=8*(lane>>4)+e (k-contig per lane) -> Alds[n][72] rows.
// B-frag: col=lane&15, same k mapping -> Blds[d][72] rows (W natural layout).
// C/D: col=lane&15 (d), row=4*(lane>>4)+reg (n)  [m89-verified].
__global__ __launch_bounds__(256) void proj_gemm_mfma(
    const unsigned short* __restrict__ Apk,  // [16][2048][2*DD]
    const unsigned short* __restrict__ Wpk,  // [2][DD][2*DD]
    const float* __restrict__ bias,
    float* __restrict__ pk, float* __restrict__ pq)
{
  __shared__ unsigned short Alds[128][72];   // 144B stride: b128 frag reads at 8-lane/window floor
  __shared__ unsigned short Blds[128][72];

  const int t = threadIdx.x;
  const int z = blockIdx.z, b = z & 7, mode = z >> 3;
  const int n0 = blockIdx.x * 128;
  const int d0 = blockIdx.y * 128;
  const int w = t >> 6, l = t & 63;
  const int wn = w & 1, wd = w >> 1;
  const int lr = l & 15, g = l >> 4;

  float4v acc[4][4];
  #pragma unroll
  for (int i = 0; i < 4; ++i)
    #pragma unroll
    for (int j = 0; j < 4; ++j) acc[i][j] = (float4v){0.f, 0.f, 0.f, 0.f};

  const int sr = t >> 1, sh = (t & 1) * 32;
  const unsigned short* asrc = Apk + ((size_t)z * 2048 + n0 + sr) * (2 * DD) + (t & 1) * DD;
  const unsigned short* bsrc = Wpk + ((size_t)mode * DD + d0 + sr) * (2 * DD) + (t & 1) * DD;

  for (int ks = 0; ks < 12; ++ks) {
    const int kt = ks * 32;
    float4 a0 = *(const float4*)(asrc + kt);
    float4 a1 = *(const float4*)(asrc + kt + 8);
    float4 a2 = *(const float4*)(asrc + kt + 16);
    float4 a3 = *(const float4*)(asrc + kt + 24);
    float4 b0 = *(const float4*)(bsrc + kt);
    float4 b1 = *(const float4*)(bsrc + kt + 8);
    float4 b2 = *(const float4*)(bsrc + kt + 16);
    float4 b3 = *(const float4*)(bsrc + kt + 24);
    __syncthreads();                       // previous iter's frag reads done
    *(float4*)&Alds[sr][sh]      = a0;
    *(float4*)&Alds[sr][sh + 8]  = a1;
    *(float4*)&Alds[sr][sh + 16] = a2;
    *(float4*)&Alds[sr][sh + 24] = a3;
    *(float4*)&Blds[sr][sh]      = b0;
    *(float4*)&Blds[sr][sh + 8]  = b1;
    *(float4*)&Blds[sr][sh + 16] = b2;
    *(float4*)&Blds[sr][sh + 24] = b3;
    __syncthreads();

    bf16x8v ah[4], al[4], bh[4], bl[4];
    #pragma unroll
    for (int i = 0; i < 4; ++i) {
      ah[i] = *(const bf16x8v*)&Alds[wn * 64 + i * 16 + lr][g * 8];
      al[i] = *(const bf16x8v*)&Alds[wn * 64 + i * 16 + lr][32 + g * 8];
      bh[i] = *(const bf16x8v*)&Blds[wd * 64 + i * 16 + lr][g * 8];
      bl[i] = *(const bf16x8v*)&Blds[wd * 64 + i * 16 + lr][32 + g * 8];
    }
    #pragma unroll
    for (int i = 0; i < 4; ++i)
      #pragma unroll
      for (int j = 0; j < 4; ++j) {
        acc[i][j] = __builtin_amdgcn_mfma_f32_16x16x32_bf16(ah[i], bh[j], acc[i][j], 0, 0, 0);
        acc[i][j] = __builtin_amdgcn_mfma_f32_16x16x32_bf16(ah[i], bl[j], acc[i][j], 0, 0, 0);
        acc[i][j] = __builtin_amdgcn_mfma_f32_16x16x32_bf16(al[i], bh[j], acc[i][j], 0, 0, 0);
      }
  }

  float bv[4];
  #pragma unroll
  for (int j = 0; j < 4; ++j)
    bv[j] = mode ? bias[d0 + wd * 64 + j * 16 + lr] : 0.f;

  float* out = (mode ? pq : pk) + (size_t)b * 2048 * DD;
  #pragma unroll
  for (int i = 0; i < 4; ++i) {
    const int nb_ = n0 + wn * 64 + i * 16 + g * 4;
    #pragma unroll
    for (int j = 0; j < 4; ++j) {
      const int dcol = d0 + wd * 64 + j * 16 + lr;
      #pragma unroll
      for (int r = 0; r < 4; ++r)
        out[(size_t)(nb_ + r) * DD + dcol] = acc[i][j][r] + bv[j];
    }
  }
}

// ===================== Fallback f32 GEMM (round-7-verified) =====================
__global__ __launch_bounds__(256) void proj_gemm_all(
    const float* __restrict__ kf, const float* __restrict__ qf,
    const float* __restrict__ W, const float* __restrict__ bias,
    float* __restrict__ pk, float* __restrict__ pq)
{
  __shared__ float At[16][128];
  __shared__ float Bt[16][132];
  const int t = threadIdx.x;
  const int z = blockIdx.z, b = z & 7, mode = z >> 3;
  const int n0 = blockIdx.x * 128, d0 = blockIdx.y * 128;
  const int td = t & 15, tn = t >> 4;
  float acc[8][8];
  #pragma unroll
  for (int i = 0; i < 8; ++i)
    #pragma unroll
    for (int j = 0; j < 8; ++j) acc[i][j] = 0.f;
  const float* feats = mode ? qf : kf;
  float* out = mode ? pq : pk;
  const float* fb = feats + (size_t)b * DD * 2048;
  const int ar = t >> 5, ac = (t & 31) * 4, bdl = t >> 2, bf = (t & 3) * 4;
  float4 sa0, sa1, sw1a, sw1b, sw2a, sw2b;
#define PREFETCH(KT)                                                           \
  {                                                                            \
    sa0 = *(const float4*)&fb[(size_t)((KT) + ar) * 2048 + n0 + ac];           \
    sa1 = *(const float4*)&fb[(size_t)((KT) + ar + 8) * 2048 + n0 + ac];       \
    const float* wr0 = W + (size_t)(d0 + bdl) * (2 * DD) + (KT) + bf;          \
    const float* wr1 = W + (size_t)(d0 + bdl + 64) * (2 * DD) + (KT) + bf;     \
    sw1a = *(const float4*)wr0; sw1b = *(const float4*)wr1;                    \
    if (mode) { sw2a = *(const float4*)(wr0 + DD); sw2b = *(const float4*)(wr1 + DD); } \
  }
  PREFETCH(0);
  for (int kt = 0; kt < DD; kt += 16) {
    *(float4*)&At[ar][ac]     = sa0;
    *(float4*)&At[ar + 8][ac] = sa1;
    {
      float4 w = sw1a;
      if (mode) { w.x = sw2a.x - w.x; w.y = sw2a.y - w.y; w.z = sw2a.z - w.z; w.w = sw2a.w - w.w; }
      Bt[bf + 0][bdl] = w.x; Bt[bf + 1][bdl] = w.y; Bt[bf + 2][bdl] = w.z; Bt[bf + 3][bdl] = w.w;
    }
    {
      float4 w = sw1b;
      if (mode) { w.x = sw2b.x - w.x; w.y = sw2b.y - w.y; w.z = sw2b.z - w.z; w.w = sw2b.w - w.w; }
      Bt[bf + 0][bdl + 64] = w.x; Bt[bf + 1][bdl + 64] = w.y; Bt[bf + 2][bdl + 64] = w.z; Bt[bf + 3][bdl + 64] = w.w;
    }
    __syncthreads();
    if (kt + 16 < DD) PREFETCH(kt + 16);
    #pragma unroll
    for (int k = 0; k < 16; ++k) {
      float a[8], bb[8];
      {
        float4 v = *(const float4*)&At[k][tn * 4];
        a[0] = v.x; a[1] = v.y; a[2] = v.z; a[3] = v.w;
        v = *(const float4*)&At[k][tn * 4 + 64];
        a[4] = v.x; a[5] = v.y; a[6] = v.z; a[7] = v.w;
        v = *(const float4*)&Bt[k][td * 4];
        bb[0] = v.x; bb[1] = v.y; bb[2] = v.z; bb[3] = v.w;
        v = *(const float4*)&Bt[k][td * 4 + 64];
        bb[4] = v.x; bb[5] = v.y; bb[6] = v.z; bb[7] = v.w;
      }
      #pragma unroll
      for (int i = 0; i < 8; ++i)
        #pragma unroll
        for (int j = 0; j < 8; ++j)
          acc[i][j] = fmaf(a[i], bb[j], acc[i][j]);
    }
    __syncthreads();
  }
#undef PREFETCH
  float4 blo = make_float4(0.f, 0.f, 0.f, 0.f);
  float4 bhi = make_float4(0.f, 0.f, 0.f, 0.f);
  if (mode) {
    blo = *(const float4*)&bias[d0 + td * 4];
    bhi = *(const float4*)&bias[d0 + td * 4 + 64];
  }
  float* ob = out + (size_t)b * 2048 * DD;
  #pragma unroll
  for (int i = 0; i < 8; ++i) {
    int n = n0 + tn * 4 + (i & 3) + ((i >= 4) ? 64 : 0);
    float4 c0, c1;
    c0.x = acc[i][0] + blo.x; c0.y = acc[i][1] + blo.y;
    c0.z = acc[i][2] + blo.z; c0.w = acc[i][3] + blo.w;
    c1.x = acc[i][4] + bhi.x; c1.y = acc[i][5] + bhi.y;
    c1.z = acc[i][6] + bhi.z; c1.w = acc[i][7] + bhi.w;
    *(float4*)&ob[(size_t)n * DD + d0 + td * 4]      = c0;
    *(float4*)&ob[(size_t)n * DD + d0 + td * 4 + 64] = c1;
  }
}

// ============== Gather + max over 8 neighbors + LeakyReLU ==============
// NOTE: pq4/out4 may alias (pq lives in d_out on the MFMA path) -> no restrict.
__global__ __launch_bounds__(384) void gather_max_kernel(
    const float4* __restrict__ pk4, const float4* pq4,
    const int* __restrict__ idx, float4* out4)
{
  const int t = threadIdx.x;
  const int bq0 = blockIdx.x * 4;
  __shared__ int nb[4][8];
  if (t < 32) nb[t >> 3][t & 7] = idx[(size_t)(bq0 + (t >> 3)) * 8 + (t & 7)];
  __syncthreads();
  const int q_l = t / 96;
  const int dv  = t - q_l * 96;
  const int bq  = bq0 + q_l;
  const int b   = bq >> 11;
  const float4* pkb = pk4 + (size_t)b * NK * 96;
  float4 m = make_float4(-FLT_MAX, -FLT_MAX, -FLT_MAX, -FLT_MAX);
  #pragma unroll
  for (int s = 0; s < 8; ++s) {
    float4 v = pkb[(size_t)nb[q_l][s] * 96 + dv];
    m.x = fmaxf(m.x, v.x); m.y = fmaxf(m.y, v.y);
    m.z = fmaxf(m.z, v.z); m.w = fmaxf(m.w, v.w);
  }
  float4 c = pq4[(size_t)bq * 96 + dv];
  float4 r;
  r.x = m.x + c.x; r.y = m.y + c.y; r.z = m.z + c.z; r.w = m.w + c.w;
  r.x = (r.x >= 0.f) ? r.x : NEG * r.x;
  r.y = (r.y >= 0.f) ? r.y : NEG * r.y;
  r.z = (r.z >= 0.f) ? r.z : NEG * r.z;
  r.w = (r.w >= 0.f) ? r.w : NEG * r.w;
  out4[(size_t)bq * 96 + dv] = r;
}

extern "C" void kernel_launch(void* const* d_in, const int* in_sizes, int n_in,
                              void* d_out, int out_size, void* d_ws, size_t ws_size,
                              hipStream_t stream) {
  const float* qc   = (const float*)d_in[0];
  const float* qf   = (const float*)d_in[1];
  const float* kc   = (const float*)d_in[2];
  const float* kf   = (const float*)d_in[3];
  const float* W    = (const float*)d_in[4];
  const float* bias = (const float*)d_in[5];
  float* out = (float*)d_out;
  char* ws = (char*)d_ws;

  const size_t APK_BYTES = (size_t)16 * 2048 * (2 * DD) * 2;  // 50,331,648
  const size_t WPK_BYTES = (size_t)2 * DD * (2 * DD) * 2;     //  1,179,648
  const size_t PK_BYTES  = (size_t)BB * NK * DD * 4;          // 25,165,824
  const size_t IDX_BYTES = (size_t)BB * NQ * 8 * 4;           //     524,288

  if (ws_size >= APK_BYTES + WPK_BYTES + PK_BYTES + IDX_BYTES) {
    unsigned short* Apk = (unsigned short*)ws;
    unsigned short* Wpk = (unsigned short*)(ws + APK_BYTES);
    float* pk = (float*)(ws + APK_BYTES + WPK_BYTES);
    int*   ix = (int*)  (ws + APK_BYTES + WPK_BYTES + PK_BYTES);
    float* pq = out;   // d_out doubles as PQ (gather reads then overwrites per-element)

    transpose_pack_kernel<<<dim3(32, 6, 16), 256, 0, stream>>>(kf, qf, Apk);
    wpack_kernel<<<dim3(DD, 2), 192, 0, stream>>>(W, Wpk);
    knn_kernel<<<dim3(NQ / (4 * QPW), BB), 256, 0, stream>>>(qc, kc, ix);
    proj_gemm_mfma<<<dim3(16, 3, 16), 256, 0, stream>>>(Apk, Wpk, bias, pk, pq);
    gather_max_kernel<<<dim3(BB * NQ / 4), 384, 0, stream>>>(
        (const float4*)pk, (const float4*)pq, ix, (float4*)out);
  } else {
    // fallback: round-7-verified f32 path (ws >= 51 MB proven by round 7)
    float* pk = (float*)ws;
    float* pq = (float*)(ws + PK_BYTES);
    int*   ix = (int*)  (ws + 2 * PK_BYTES);
    knn_kernel<<<dim3(NQ / (4 * QPW), BB), 256, 0, stream>>>(qc, kc, ix);
    proj_gemm_all<<<dim3(16, 3, 16), 256, 0, stream>>>(kf, qf, W, bias, pk, pq);
    gather_max_kernel<<<dim3(BB * NQ / 4), 384, 0, stream>>>(
        (const float4*)pk, (const float4*)pq, ix, (float4*)out);
  }
}